// Round 4
// baseline (355.270 us; speedup 1.0000x reference)
//
#include <hip/hip_runtime.h>
#include <math.h>

#define B_BAGS 8
#define N_INST 8192
#define D_DIM  512
#define H_ATT  64
#define TOPK_K 2457
#define ROWS_TOTAL (B_BAGS * N_INST)

typedef __attribute__((ext_vector_type(8))) short bf16x8;
typedef __attribute__((ext_vector_type(4))) float f32x4;

// ---- workspace layout (bytes) ----
#define WS_W1P_HI 0                          // packed MFMA B-frags, 32768 ushort
#define WS_W1P_LO 65536                      // packed MFMA B-frags, 32768 ushort
#define WS_EMB    131584                     // [8][512] f32 atomic emb accumulator (16 KB)
#define WS_CNT    (WS_EMB + 8*512*4)         // [8] arrival counters
#define WS_THRESH (WS_CNT + 64)              // [8] x {T, Icut} uint pairs

__device__ __forceinline__ unsigned short bf16_rn(float f) {
  unsigned int x = __float_as_uint(f);
  unsigned int r = (x + 0x7FFFu + ((x >> 16) & 1u)) >> 16;
  return (unsigned short)r;
}
__device__ __forceinline__ float bf16_f(unsigned short u) {
  return __uint_as_float(((unsigned int)u) << 16);
}
__device__ __forceinline__ float gelu_f(float v) {
  float u = 0.7978845608028654f * (v + 0.044715f * v * v * v);
  return 0.5f * v * (1.0f + tanhf(u));
}

// truncation-based hi/lo split of 8 consecutive fp32 -> bf16x8 hi + lo.
__device__ __forceinline__ void cvt_hilo(const float4 u, const float4 v,
                                         bf16x8& h, bf16x8& l) {
  float f[8] = {u.x, u.y, u.z, u.w, v.x, v.y, v.z, v.w};
#pragma unroll
  for (int i = 0; i < 8; i++) {
    unsigned int b = __float_as_uint(f[i]);
    unsigned int hb = b & 0xFFFF0000u;
    float r = f[i] - __uint_as_float(hb);
    h[i] = (short)(b >> 16);
    l[i] = (short)(__float_as_uint(r) >> 16);
  }
}

// async global->LDS DMA, 16B per lane. LDS dest = wave-uniform base + lane*16.
__device__ __forceinline__ void load_lds16(const void* g, void* l) {
  __builtin_amdgcn_global_load_lds(
      (const __attribute__((address_space(1))) void*)g,
      (__attribute__((address_space(3))) void*)l, 16, 0, 0);
}

// ---------------- kernel 0: pack aW1 + zero emb/cnt for this iteration ------
__global__ __launch_bounds__(256) void k_prep(const float* __restrict__ aW1,
                                              unsigned short* __restrict__ hi,
                                              unsigned short* __restrict__ lo,
                                              float* __restrict__ emb_acc,
                                              unsigned int* __restrict__ cnt) {
  int tau = blockIdx.x * 256 + threadIdx.x;   // (ks,t,lane) tuple, 4096 total
  if (tau >= 4096) return;
  emb_acc[tau] = 0.f;          // [8][512] accumulator re-zeroed every replay
  if (tau < 8) cnt[tau] = 0u;  // arrival counters
  int ks = tau >> 8, t = (tau >> 6) & 3, lane = tau & 63;
  int n = t * 16 + (lane & 15);
  int kb = ks * 32 + (lane >> 4) * 8;
#pragma unroll
  for (int j = 0; j < 8; j++) {
    float v = aW1[(kb + j) * H_ATT + n];
    unsigned short h = bf16_rn(v);
    unsigned short l = bf16_rn(v - bf16_f(h));
    hi[tau * 8 + j] = h;
    lo[tau * 8 + j] = l;
  }
}

// ---------------- kernel 1: score MLP -> sigmoid weights ----------------
// 2-phase pipelined staging, K-chunk 32, double-buffered LDS (33 KB, 4 blk/CU).
#define BM 64
#define NCH 16
#define AUNIT2 1040           // 8 rows x 128 B + 16 B pad
#define ABUF (8 * AUNIT2)     // 8320 B per A buffer

__global__ __launch_bounds__(256) void k_scores(
    const float* __restrict__ x,
    const unsigned short* __restrict__ w1p_hi,
    const unsigned short* __restrict__ w1p_lo,
    const float* __restrict__ ab1, const float* __restrict__ aW2,
    const float* __restrict__ ab2, float* __restrict__ wout) {
  __shared__ __align__(16) char Asm[2][ABUF];
  __shared__ __align__(16) char Bhs[2][4096];
  __shared__ __align__(16) char Bls[2][4096];

  int tid = threadIdx.x;
  int wave = tid >> 6, lane = tid & 63;
  int c0 = lane & 15, quad = lane >> 4;
  int rowBase0 = blockIdx.x * BM;

  f32x4 acc[4];
#pragma unroll
  for (int t = 0; t < 4; t++) acc[t] = (f32x4){0.f, 0.f, 0.f, 0.f};

  const int r = wave * 16 + c0;        // row within block this lane computes
  const int aoff = (r >> 3) * AUNIT2 + (r & 7) * 128 + quad * 32;

  auto stage = [&](int c, int pb) {
#pragma unroll
    for (int i = 0; i < 2; i++) {
      int u = wave * 2 + i;
      const char* g = (const char*)x +
          (size_t)(rowBase0 + u * 8 + (lane >> 3)) * 2048 +
          (size_t)c * 128 + (size_t)(lane & 7) * 16;
      load_lds16(g, &Asm[pb][u * AUNIT2]);
    }
    load_lds16((const char*)w1p_hi + (size_t)c * 4096 + wave * 1024 + lane * 16,
               &Bhs[pb][wave * 1024]);
    load_lds16((const char*)w1p_lo + (size_t)c * 4096 + wave * 1024 + lane * 16,
               &Bls[pb][wave * 1024]);
  };

  stage(0, 0);
  __syncthreads();   // drain prologue DMA

  for (int c = 0; c < NCH; c++) {
    int pb = c & 1;
    if (c + 1 < NCH) stage(c + 1, pb ^ 1);   // issue-early: overlap w/ compute

    const float4 a0v = *reinterpret_cast<const float4*>(&Asm[pb][aoff]);
    const float4 a1v = *reinterpret_cast<const float4*>(&Asm[pb][aoff + 16]);
    bf16x8 afh, afl;
    cvt_hilo(a0v, a1v, afh, afl);
    bf16x8 bfh[4], bfl[4];
#pragma unroll
    for (int t = 0; t < 4; t++) {
      bfh[t] = *reinterpret_cast<const bf16x8*>(&Bhs[pb][t * 1024 + lane * 16]);
      bfl[t] = *reinterpret_cast<const bf16x8*>(&Bls[pb][t * 1024 + lane * 16]);
    }
#pragma unroll
    for (int t = 0; t < 4; t++) {
      acc[t] = __builtin_amdgcn_mfma_f32_16x16x32_bf16(afl, bfh[t], acc[t], 0, 0, 0);
      acc[t] = __builtin_amdgcn_mfma_f32_16x16x32_bf16(afh, bfl[t], acc[t], 0, 0, 0);
      acc[t] = __builtin_amdgcn_mfma_f32_16x16x32_bf16(afh, bfh[t], acc[t], 0, 0, 0);
    }
    __syncthreads();   // vmcnt(0)+barrier: next buf ready, this buf reusable
  }

  // epilogue: h = gelu(acc + ab1); score = h @ aW2 + ab2; w = sigmoid(score)
  float w2v[4], b1v[4];
#pragma unroll
  for (int t = 0; t < 4; t++) {
    w2v[t] = aW2[t * 16 + c0];
    b1v[t] = ab1[t * 16 + c0];
  }
  float bias2 = ab2[0];
  float p[4] = {0.f, 0.f, 0.f, 0.f};
#pragma unroll
  for (int t = 0; t < 4; t++)
#pragma unroll
    for (int rr = 0; rr < 4; rr++) {
      float h = gelu_f(acc[t][rr] + b1v[t]);
      p[rr] += h * w2v[t];
    }
#pragma unroll
  for (int off = 1; off < 16; off <<= 1)
#pragma unroll
    for (int rr = 0; rr < 4; rr++) p[rr] += __shfl_xor(p[rr], off, 64);
  if (c0 == 0) {
    int row = rowBase0 + wave * 16 + quad * 4;
#pragma unroll
    for (int rr = 0; rr < 4; rr++) {
      float sc = p[rr] + bias2;
      wout[row + rr] = 1.0f / (1.0f + expf(-sc));
    }
  }
}

// ---------------- kernel 1b: per-bag top-k threshold (once per bag) ----------
__global__ __launch_bounds__(256) void k_thresh(const float* __restrict__ wout,
                                                unsigned int* __restrict__ thr) {
  int b = blockIdx.x;
  int tid = threadIdx.x;
  const float* w = wout + b * N_INST;

  unsigned int v[32];
#pragma unroll
  for (int j = 0; j < 32; j++) v[j] = __float_as_uint(w[j * 256 + tid]);

  __shared__ int red[2][4];
  int lane = tid & 63, wv = tid >> 6;
  int pb = 0;
  auto blocksum = [&](int c) -> int {
#pragma unroll
    for (int off = 32; off > 0; off >>= 1) c += __shfl_down(c, off, 64);
    if (lane == 0) red[pb][wv] = c;
    __syncthreads();
    int s = red[pb][0] + red[pb][1] + red[pb][2] + red[pb][3];
    pb ^= 1;
    return s;
  };

  unsigned int lo = 0u, hi = 0x3F800001u;
  while (hi - lo > 1u) {
    unsigned int mid = lo + ((hi - lo) >> 1);
    int c = 0;
#pragma unroll
    for (int j = 0; j < 32; j++) c += (v[j] >= mid) ? 1 : 0;
    if (blocksum(c) >= TOPK_K) lo = mid; else hi = mid;
  }
  unsigned int T = lo;
  int c1 = 0;
#pragma unroll
  for (int j = 0; j < 32; j++) c1 += (v[j] > T) ? 1 : 0;
  c1 = blocksum(c1);
  int needed = TOPK_K - c1;  // >= 1
  unsigned int tm = 0;
#pragma unroll
  for (int j = 0; j < 32; j++) tm |= (v[j] == T ? 1u : 0u) << j;
  int lom = -1, him = N_INST - 1;
  while (him - lom > 1) {
    int mid = (lom + him) >> 1;
    unsigned int mask = 0u;
    if (mid >= tid) {
      unsigned int jmax = (unsigned int)(mid - tid) >> 8;
      mask = (2u << jmax) - 1u;
    }
    if (blocksum((int)__popc(tm & mask)) >= needed) him = mid; else lom = mid;
  }
  if (tid == 0) {
    thr[b * 2] = T;
    thr[b * 2 + 1] = (unsigned int)him;   // Icut
  }
}

// ---------------- kernel 2: gather + full projection MLP (fused tail) --------
// 64 blocks/bag gather their selected rows and atomically accumulate the
// weighted sum into emb_acc[b][512] (device-scope f32 atomics). The last
// arriving block of each bag (atomic counter) then runs the entire
// 512->512(gelu)->512 projection for that bag and writes out directly.
__global__ __launch_bounds__(256) void k_gatherproj(
    const float* __restrict__ x, const float* __restrict__ wout,
    const unsigned int* __restrict__ thr,
    const float* __restrict__ pW1, const float* __restrict__ pb1,
    const float* __restrict__ pW2, const float* __restrict__ pb2,
    float* __restrict__ emb_acc, unsigned int* __restrict__ cnt,
    float* __restrict__ out) {
  int b = blockIdx.x >> 6;
  int blk = blockIdx.x & 63;
  int tid = threadIdx.x;
  const float* w = wout + b * N_INST;

  unsigned int T = thr[b * 2];
  int Icut = (int)thr[b * 2 + 1];

  __shared__ int idxs[128];
  __shared__ float wgts[128];
  __shared__ int wcnt[2];
  __shared__ float4 xfer[128];
  __shared__ float ebuf[512];
  __shared__ float hbuf[512];
  __shared__ int lastflag;

  int lane = tid & 63;
  int r = blk * 128 + tid;
  bool sel = false;
  float wvv = 0.f;
  int pos = 0;
  if (tid < 128) {
    wvv = w[r];
    unsigned int wu = __float_as_uint(wvv);
    sel = (wu > T) || (wu == T && r <= Icut);
    unsigned long long m = __ballot(sel);
    pos = __popcll(m & ((1ull << lane) - 1ull));
    if (lane == 0) wcnt[tid >> 6] = __popcll(m);
  }
  __syncthreads();
  int total = wcnt[0] + wcnt[1];
  if (sel) {
    int base = (tid >= 64) ? wcnt[0] : 0;
    idxs[base + pos] = r;
    wgts[base + pos] = wvv;
  }
  __syncthreads();

  int half = tid >> 7;
  int L = tid & 127;
  float4 acc = {0.f, 0.f, 0.f, 0.f};
  const float* xb = x + (size_t)b * N_INST * D_DIM;
  int i2 = total & ~1;
#pragma unroll 4
  for (int i = 0; i < i2; i += 2) {
    int rr = idxs[i + half];
    float ww = wgts[i + half];
    const float4 xv = *reinterpret_cast<const float4*>(xb + (size_t)rr * D_DIM + L * 4);
    acc.x += ww * xv.x; acc.y += ww * xv.y; acc.z += ww * xv.z; acc.w += ww * xv.w;
  }
  if ((total & 1) && half == 0) {
    int rr = idxs[i2];
    float ww = wgts[i2];
    const float4 xv = *reinterpret_cast<const float4*>(xb + (size_t)rr * D_DIM + L * 4);
    acc.x += ww * xv.x; acc.y += ww * xv.y; acc.z += ww * xv.z; acc.w += ww * xv.w;
  }
  if (half == 1) xfer[L] = acc;
  __syncthreads();
  if (half == 0) {
    float4 o = xfer[L];
    acc.x += o.x; acc.y += o.y; acc.z += o.z; acc.w += o.w;
    float* e = emb_acc + (size_t)b * D_DIM + L * 4;
    atomicAdd(e + 0, acc.x);
    atomicAdd(e + 1, acc.y);
    atomicAdd(e + 2, acc.z);
    atomicAdd(e + 3, acc.w);
  }

  // release: my atomics visible device-wide, then signal arrival
  __threadfence();
  __syncthreads();
  if (tid == 0) {
    unsigned int old = atomicAdd(&cnt[b], 1u);
    lastflag = (old == 63u) ? 1 : 0;
  }
  __syncthreads();
  if (!lastflag) return;

  // last block of bag b: acquire emb, run the projection MLP
  __threadfence();
  for (int k = tid; k < D_DIM; k += 256) {
    float v = __hip_atomic_load(&emb_acc[(size_t)b * D_DIM + k],
                                __ATOMIC_ACQUIRE, __HIP_MEMORY_SCOPE_AGENT);
    ebuf[k] = v * (1.0f / TOPK_K);
  }
  __syncthreads();
  {
    int j0 = tid * 2;
    float s0 = pb1[j0], s1 = pb1[j0 + 1];
#pragma unroll 8
    for (int k = 0; k < D_DIM; k++) {
      float e = ebuf[k];
      const float2 wv = *reinterpret_cast<const float2*>(&pW1[(size_t)k * D_DIM + j0]);
      s0 += e * wv.x; s1 += e * wv.y;
    }
    hbuf[j0] = gelu_f(s0);
    hbuf[j0 + 1] = gelu_f(s1);
  }
  __syncthreads();
  {
    int d0 = tid * 2;
    float s0 = pb2[d0], s1 = pb2[d0 + 1];
#pragma unroll 8
    for (int k = 0; k < D_DIM; k++) {
      float h = hbuf[k];
      const float2 wv = *reinterpret_cast<const float2*>(&pW2[(size_t)k * D_DIM + d0]);
      s0 += h * wv.x; s1 += h * wv.y;
    }
    out[b * D_DIM + d0] = s0;
    out[b * D_DIM + d0 + 1] = s1;
  }
}

extern "C" void kernel_launch(void* const* d_in, const int* in_sizes, int n_in,
                              void* d_out, int out_size, void* d_ws, size_t ws_size,
                              hipStream_t stream) {
  (void)in_sizes; (void)n_in; (void)out_size; (void)ws_size;
  const float* x   = (const float*)d_in[0];
  const float* aW1 = (const float*)d_in[1];
  const float* ab1 = (const float*)d_in[2];
  const float* aW2 = (const float*)d_in[3];
  const float* ab2 = (const float*)d_in[4];
  const float* pW1 = (const float*)d_in[5];
  const float* pb1 = (const float*)d_in[6];
  const float* pW2 = (const float*)d_in[7];
  const float* pb2 = (const float*)d_in[8];

  float* out  = (float*)d_out;
  float* wout = out + B_BAGS * D_DIM;  // weights output region [8][8192]

  char* ws = (char*)d_ws;
  unsigned short* w1p_hi = (unsigned short*)(ws + WS_W1P_HI);
  unsigned short* w1p_lo = (unsigned short*)(ws + WS_W1P_LO);
  float* emb_acc = (float*)(ws + WS_EMB);
  unsigned int* cnt = (unsigned int*)(ws + WS_CNT);
  unsigned int* thr = (unsigned int*)(ws + WS_THRESH);

  k_prep<<<dim3(16), dim3(256), 0, stream>>>(aW1, w1p_hi, w1p_lo, emb_acc, cnt);
  k_scores<<<dim3(ROWS_TOTAL / BM), dim3(256), 0, stream>>>(x, w1p_hi, w1p_lo, ab1, aW2, ab2, wout);
  k_thresh<<<dim3(B_BAGS), dim3(256), 0, stream>>>(wout, thr);
  k_gatherproj<<<dim3(B_BAGS * 64), dim3(256), 0, stream>>>(
      x, wout, thr, pW1, pb1, pW2, pb2, emb_acc, cnt, out);
}

// Round 5
// 261.476 us; speedup vs baseline: 1.3587x; 1.3587x over previous
//
#include <hip/hip_runtime.h>
#include <math.h>

#define B_BAGS 8
#define N_INST 8192
#define D_DIM  512
#define H_ATT  64
#define TOPK_K 2457
#define ROWS_TOTAL (B_BAGS * N_INST)

typedef __attribute__((ext_vector_type(8))) short bf16x8;
typedef __attribute__((ext_vector_type(4))) float f32x4;

// ---- workspace layout (bytes) ----
#define WS_W1P_HI 0                          // packed MFMA B-frags, 32768 ushort
#define WS_W1P_LO 65536                      // packed MFMA B-frags, 32768 ushort
#define WS_PART3  131584                     // [8][64][512] f32 gather partials (1 MB)
#define WS_PART1  (WS_PART3 + 8*64*512*4)    // [16kt][8b][512] f32 layer1 partials (256 KB)
#define WS_THRESH (WS_PART1 + 16*8*512*4)    // [8] x {T, Icut} uint pairs

__device__ __forceinline__ unsigned short bf16_rn(float f) {
  unsigned int x = __float_as_uint(f);
  unsigned int r = (x + 0x7FFFu + ((x >> 16) & 1u)) >> 16;
  return (unsigned short)r;
}
__device__ __forceinline__ float bf16_f(unsigned short u) {
  return __uint_as_float(((unsigned int)u) << 16);
}
__device__ __forceinline__ float gelu_f(float v) {
  float u = 0.7978845608028654f * (v + 0.044715f * v * v * v);
  return 0.5f * v * (1.0f + tanhf(u));
}

// truncation-based hi/lo split of 8 consecutive fp32 -> bf16x8 hi + lo.
__device__ __forceinline__ void cvt_hilo(const float4 u, const float4 v,
                                         bf16x8& h, bf16x8& l) {
  float f[8] = {u.x, u.y, u.z, u.w, v.x, v.y, v.z, v.w};
#pragma unroll
  for (int i = 0; i < 8; i++) {
    unsigned int b = __float_as_uint(f[i]);
    unsigned int hb = b & 0xFFFF0000u;
    float r = f[i] - __uint_as_float(hb);
    h[i] = (short)(b >> 16);
    l[i] = (short)(__float_as_uint(r) >> 16);
  }
}

// ---------------- kernel 0: pack aW1 into MFMA-fragment-sequential layout ----
__global__ __launch_bounds__(256) void k_prep(const float* __restrict__ aW1,
                                              unsigned short* __restrict__ hi,
                                              unsigned short* __restrict__ lo) {
  int tau = blockIdx.x * 256 + threadIdx.x;   // (ks,t,lane) tuple, 4096 total
  if (tau >= 4096) return;
  int ks = tau >> 8, t = (tau >> 6) & 3, lane = tau & 63;
  int n = t * 16 + (lane & 15);
  int kb = ks * 32 + (lane >> 4) * 8;
#pragma unroll
  for (int j = 0; j < 8; j++) {
    float v = aW1[(kb + j) * H_ATT + n];
    unsigned short h = bf16_rn(v);
    unsigned short l = bf16_rn(v - bf16_f(h));
    hi[tau * 8 + j] = h;
    lo[tau * 8 + j] = l;
  }
}

// ---------------- kernel 1: score MLP -> sigmoid weights ----------------
// Pure-dataflow version: NO LDS, NO barriers. The MFMA A-fragment for lane
// (c0,quad) is 8 consecutive floats of one x row -> two direct float4 loads.
// B-fragments are lane-linear in w1p_hi/lo (designed so) and L2-resident
// (128 KB) -> direct bf16x8 loads. Compiler pipelines loads across chunks;
// no vmcnt(0) drains, no inter-wave lockstep. Values / MFMA order identical
// to the staged version -> bitwise-identical results.
#define BM 64
#define NCH 16

__global__ __launch_bounds__(256) void k_scores(
    const float* __restrict__ x,
    const unsigned short* __restrict__ w1p_hi,
    const unsigned short* __restrict__ w1p_lo,
    const float* __restrict__ ab1, const float* __restrict__ aW2,
    const float* __restrict__ ab2, float* __restrict__ wout) {
  int tid = threadIdx.x;
  int wave = tid >> 6, lane = tid & 63;
  int c0 = lane & 15, quad = lane >> 4;
  int rowBase0 = blockIdx.x * BM;

  const int row = rowBase0 + wave * 16 + c0;   // this lane's A row
  const float* arow = x + (size_t)row * D_DIM;

  f32x4 acc[4];
#pragma unroll
  for (int t = 0; t < 4; t++) acc[t] = (f32x4){0.f, 0.f, 0.f, 0.f};

#pragma unroll 2
  for (int c = 0; c < NCH; c++) {
    const float* ap = arow + c * 32 + quad * 8;
    const float4 a0v = *reinterpret_cast<const float4*>(ap);
    const float4 a1v = *reinterpret_cast<const float4*>(ap + 4);
    bf16x8 afh, afl;
    cvt_hilo(a0v, a1v, afh, afl);
    bf16x8 bfh[4], bfl[4];
#pragma unroll
    for (int t = 0; t < 4; t++) {
      size_t fo = ((size_t)(c * 4 + t) * 64 + lane) * 8;
      bfh[t] = *reinterpret_cast<const bf16x8*>(w1p_hi + fo);
      bfl[t] = *reinterpret_cast<const bf16x8*>(w1p_lo + fo);
    }
#pragma unroll
    for (int t = 0; t < 4; t++) {
      acc[t] = __builtin_amdgcn_mfma_f32_16x16x32_bf16(afl, bfh[t], acc[t], 0, 0, 0);
      acc[t] = __builtin_amdgcn_mfma_f32_16x16x32_bf16(afh, bfl[t], acc[t], 0, 0, 0);
      acc[t] = __builtin_amdgcn_mfma_f32_16x16x32_bf16(afh, bfh[t], acc[t], 0, 0, 0);
    }
  }

  // epilogue: h = gelu(acc + ab1); score = h @ aW2 + ab2; w = sigmoid(score)
  float w2v[4], b1v[4];
#pragma unroll
  for (int t = 0; t < 4; t++) {
    w2v[t] = aW2[t * 16 + c0];
    b1v[t] = ab1[t * 16 + c0];
  }
  float bias2 = ab2[0];
  float p[4] = {0.f, 0.f, 0.f, 0.f};
#pragma unroll
  for (int t = 0; t < 4; t++)
#pragma unroll
    for (int rr = 0; rr < 4; rr++) {
      float h = gelu_f(acc[t][rr] + b1v[t]);
      p[rr] += h * w2v[t];
    }
#pragma unroll
  for (int off = 1; off < 16; off <<= 1)
#pragma unroll
    for (int rr = 0; rr < 4; rr++) p[rr] += __shfl_xor(p[rr], off, 64);
  if (c0 == 0) {
    int orow = rowBase0 + wave * 16 + quad * 4;
#pragma unroll
    for (int rr = 0; rr < 4; rr++) {
      float sc = p[rr] + bias2;
      wout[orow + rr] = 1.0f / (1.0f + expf(-sc));
    }
  }
}

// ---------------- kernel 1b: per-bag top-k threshold (once per bag) ----------
__global__ __launch_bounds__(256) void k_thresh(const float* __restrict__ wout,
                                                unsigned int* __restrict__ thr) {
  int b = blockIdx.x;
  int tid = threadIdx.x;
  const float* w = wout + b * N_INST;

  unsigned int v[32];
#pragma unroll
  for (int j = 0; j < 32; j++) v[j] = __float_as_uint(w[j * 256 + tid]);

  __shared__ int red[2][4];
  int lane = tid & 63, wv = tid >> 6;
  int pb = 0;
  auto blocksum = [&](int c) -> int {
#pragma unroll
    for (int off = 32; off > 0; off >>= 1) c += __shfl_down(c, off, 64);
    if (lane == 0) red[pb][wv] = c;
    __syncthreads();
    int s = red[pb][0] + red[pb][1] + red[pb][2] + red[pb][3];
    pb ^= 1;
    return s;
  };

  unsigned int lo = 0u, hi = 0x3F800001u;
  while (hi - lo > 1u) {
    unsigned int mid = lo + ((hi - lo) >> 1);
    int c = 0;
#pragma unroll
    for (int j = 0; j < 32; j++) c += (v[j] >= mid) ? 1 : 0;
    if (blocksum(c) >= TOPK_K) lo = mid; else hi = mid;
  }
  unsigned int T = lo;
  int c1 = 0;
#pragma unroll
  for (int j = 0; j < 32; j++) c1 += (v[j] > T) ? 1 : 0;
  c1 = blocksum(c1);
  int needed = TOPK_K - c1;  // >= 1
  unsigned int tm = 0;
#pragma unroll
  for (int j = 0; j < 32; j++) tm |= (v[j] == T ? 1u : 0u) << j;
  int lom = -1, him = N_INST - 1;
  while (him - lom > 1) {
    int mid = (lom + him) >> 1;
    unsigned int mask = 0u;
    if (mid >= tid) {
      unsigned int jmax = (unsigned int)(mid - tid) >> 8;
      mask = (2u << jmax) - 1u;
    }
    if (blocksum((int)__popc(tm & mask)) >= needed) him = mid; else lom = mid;
  }
  if (tid == 0) {
    thr[b * 2] = T;
    thr[b * 2 + 1] = (unsigned int)him;   // Icut
  }
}

// ---------------- kernel 2: selection + weighted gather ----------------
__global__ __launch_bounds__(256) void k_gather(const float* __restrict__ x,
                                                const float* __restrict__ wout,
                                                const unsigned int* __restrict__ thr,
                                                float* __restrict__ part3) {
  int b = blockIdx.x >> 6;
  int blk = blockIdx.x & 63;
  int tid = threadIdx.x;
  const float* w = wout + b * N_INST;

  unsigned int T = thr[b * 2];
  int Icut = (int)thr[b * 2 + 1];

  __shared__ int idxs[128];
  __shared__ float wgts[128];
  __shared__ int wcnt[2];
  __shared__ float4 xfer[128];

  int lane = tid & 63;
  int r = blk * 128 + tid;
  bool sel = false;
  float wvv = 0.f;
  int pos = 0;
  if (tid < 128) {
    wvv = w[r];
    unsigned int wu = __float_as_uint(wvv);
    sel = (wu > T) || (wu == T && r <= Icut);
    unsigned long long m = __ballot(sel);
    pos = __popcll(m & ((1ull << lane) - 1ull));
    if (lane == 0) wcnt[tid >> 6] = __popcll(m);
  }
  __syncthreads();
  int total = wcnt[0] + wcnt[1];
  if (sel) {
    int base = (tid >= 64) ? wcnt[0] : 0;
    idxs[base + pos] = r;
    wgts[base + pos] = wvv;
  }
  __syncthreads();

  int half = tid >> 7;
  int L = tid & 127;
  float4 acc = {0.f, 0.f, 0.f, 0.f};
  const float* xb = x + (size_t)b * N_INST * D_DIM;
  int i2 = total & ~1;
#pragma unroll 4
  for (int i = 0; i < i2; i += 2) {
    int rr = idxs[i + half];
    float ww = wgts[i + half];
    const float4 xv = *reinterpret_cast<const float4*>(xb + (size_t)rr * D_DIM + L * 4);
    acc.x += ww * xv.x; acc.y += ww * xv.y; acc.z += ww * xv.z; acc.w += ww * xv.w;
  }
  if ((total & 1) && half == 0) {
    int rr = idxs[i2];
    float ww = wgts[i2];
    const float4 xv = *reinterpret_cast<const float4*>(xb + (size_t)rr * D_DIM + L * 4);
    acc.x += ww * xv.x; acc.y += ww * xv.y; acc.z += ww * xv.z; acc.w += ww * xv.w;
  }
  if (half == 1) xfer[L] = acc;
  __syncthreads();
  if (half == 0) {
    float4 o = xfer[L];
    acc.x += o.x; acc.y += o.y; acc.z += o.z; acc.w += o.w;
    *reinterpret_cast<float4*>(part3 + (size_t)(b * 64 + blk) * D_DIM + L * 4) = acc;
  }
}

// ---------------- projection MLP: split-K x16; layer2 accumulates into out ----
__global__ __launch_bounds__(256) void k_proj1(const float* __restrict__ part3,
                                               const float* __restrict__ pW1,
                                               float* __restrict__ part1,
                                               const float* __restrict__ pb2,
                                               float* __restrict__ out) {
  int jt = blockIdx.x & 7, kt = blockIdx.x >> 3;   // kt in [0,16)
  __shared__ float emb_s[256];                      // [8 bags][32 dims]
  int tid = threadIdx.x;
  int col = tid & 63, bg = tid >> 6;
  if (kt == 0) {
    float bz = pb2[jt * 64 + col];
    out[(bg * 2) * 512 + jt * 64 + col] = bz;
    out[(bg * 2 + 1) * 512 + jt * 64 + col] = bz;
  }
  {
    int b = tid >> 5, d0 = tid & 31;
    const float* p = part3 + (size_t)b * 64 * 512 + kt * 32 + d0;
    float e = 0.f;
#pragma unroll 8
    for (int j = 0; j < 64; j++) e += p[j * 512];
    emb_s[b * 32 + d0] = e * (1.0f / TOPK_K);
  }
  __syncthreads();
  float a0 = 0.f, a1 = 0.f;
  const float* wrow = pW1 + (size_t)(kt * 32) * 512 + jt * 64 + col;
#pragma unroll 8
  for (int q = 0; q < 32; q++) {
    float wq = wrow[q * 512];
    a0 += emb_s[(bg * 2) * 32 + q] * wq;
    a1 += emb_s[(bg * 2 + 1) * 32 + q] * wq;
  }
  part1[kt * 4096 + (bg * 2) * 512 + jt * 64 + col] = a0;
  part1[kt * 4096 + (bg * 2 + 1) * 512 + jt * 64 + col] = a1;
}

__global__ __launch_bounds__(256) void k_proj2(const float* __restrict__ part1,
                                               const float* __restrict__ pb1,
                                               const float* __restrict__ pW2,
                                               float* __restrict__ out) {
  int jt = blockIdx.x & 7, kt = blockIdx.x >> 3;   // kt in [0,16)
  __shared__ float h_s[256];                        // [8 bags][32 hidden]
  int tid = threadIdx.x;
  {
    int b = tid >> 5, j0 = tid & 31;
    int jj = kt * 32 + j0;
    float s = pb1[jj];
#pragma unroll
    for (int p = 0; p < 16; p++) s += part1[p * 4096 + b * 512 + jj];
    h_s[b * 32 + j0] = gelu_f(s);
  }
  __syncthreads();
  int col = tid & 63, bg = tid >> 6;
  float a0 = 0.f, a1 = 0.f;
  const float* wrow = pW2 + (size_t)(kt * 32) * 512 + jt * 64 + col;
#pragma unroll 8
  for (int q = 0; q < 32; q++) {
    float wq = wrow[q * 512];
    a0 += h_s[(bg * 2) * 32 + q] * wq;
    a1 += h_s[(bg * 2 + 1) * 32 + q] * wq;
  }
  atomicAdd(&out[(bg * 2) * 512 + jt * 64 + col], a0);
  atomicAdd(&out[(bg * 2 + 1) * 512 + jt * 64 + col], a1);
}

extern "C" void kernel_launch(void* const* d_in, const int* in_sizes, int n_in,
                              void* d_out, int out_size, void* d_ws, size_t ws_size,
                              hipStream_t stream) {
  (void)in_sizes; (void)n_in; (void)out_size; (void)ws_size;
  const float* x   = (const float*)d_in[0];
  const float* aW1 = (const float*)d_in[1];
  const float* ab1 = (const float*)d_in[2];
  const float* aW2 = (const float*)d_in[3];
  const float* ab2 = (const float*)d_in[4];
  const float* pW1 = (const float*)d_in[5];
  const float* pb1 = (const float*)d_in[6];
  const float* pW2 = (const float*)d_in[7];
  const float* pb2 = (const float*)d_in[8];

  float* out  = (float*)d_out;
  float* wout = out + B_BAGS * D_DIM;  // weights output region [8][8192]

  char* ws = (char*)d_ws;
  unsigned short* w1p_hi = (unsigned short*)(ws + WS_W1P_HI);
  unsigned short* w1p_lo = (unsigned short*)(ws + WS_W1P_LO);
  float* part3 = (float*)(ws + WS_PART3);
  float* part1 = (float*)(ws + WS_PART1);
  unsigned int* thr = (unsigned int*)(ws + WS_THRESH);

  k_prep<<<dim3(16), dim3(256), 0, stream>>>(aW1, w1p_hi, w1p_lo);
  k_scores<<<dim3(ROWS_TOTAL / BM), dim3(256), 0, stream>>>(x, w1p_hi, w1p_lo, ab1, aW2, ab2, wout);
  k_thresh<<<dim3(B_BAGS), dim3(256), 0, stream>>>(wout, thr);
  k_gather<<<dim3(B_BAGS * 64), dim3(256), 0, stream>>>(x, wout, thr, part3);
  k_proj1<<<dim3(128), dim3(256), 0, stream>>>(part3, pW1, part1, pb2, out);
  k_proj2<<<dim3(128), dim3(256), 0, stream>>>(part1, pb1, pW2, out);
}

// Round 6
// 254.306 us; speedup vs baseline: 1.3970x; 1.0282x over previous
//
#include <hip/hip_runtime.h>
#include <math.h>

#define B_BAGS 8
#define N_INST 8192
#define D_DIM  512
#define H_ATT  64
#define TOPK_K 2457
#define ROWS_TOTAL (B_BAGS * N_INST)

typedef __attribute__((ext_vector_type(8))) short bf16x8;
typedef __attribute__((ext_vector_type(4))) float f32x4;

// ---- workspace layout (bytes) ----
#define WS_W1P_HI 0                          // packed MFMA B-frags, 32768 ushort
#define WS_W1P_LO 65536                      // packed MFMA B-frags, 32768 ushort
#define WS_PART3  131584                     // [8][64][512] f32 gather partials (1 MB)
#define WS_PART1  (WS_PART3 + 8*64*512*4)    // [16kt][8b][512] f32 layer1 partials (256 KB)
#define WS_THRESH (WS_PART1 + 16*8*512*4)    // [8] x {T, Icut} uint pairs

__device__ __forceinline__ unsigned short bf16_rn(float f) {
  unsigned int x = __float_as_uint(f);
  unsigned int r = (x + 0x7FFFu + ((x >> 16) & 1u)) >> 16;
  return (unsigned short)r;
}
__device__ __forceinline__ float bf16_f(unsigned short u) {
  return __uint_as_float(((unsigned int)u) << 16);
}
__device__ __forceinline__ float gelu_f(float v) {
  float u = 0.7978845608028654f * (v + 0.044715f * v * v * v);
  return 0.5f * v * (1.0f + tanhf(u));
}

// truncation-based hi/lo split of 8 consecutive fp32 -> bf16x8 hi + lo.
__device__ __forceinline__ void cvt_hilo(const float4 u, const float4 v,
                                         bf16x8& h, bf16x8& l) {
  float f[8] = {u.x, u.y, u.z, u.w, v.x, v.y, v.z, v.w};
#pragma unroll
  for (int i = 0; i < 8; i++) {
    unsigned int b = __float_as_uint(f[i]);
    unsigned int hb = b & 0xFFFF0000u;
    float r = f[i] - __uint_as_float(hb);
    h[i] = (short)(b >> 16);
    l[i] = (short)(__float_as_uint(r) >> 16);
  }
}

// async global->LDS DMA, 16B per lane. LDS dest = wave-uniform base + lane*16.
__device__ __forceinline__ void load_lds16(const void* g, void* l) {
  __builtin_amdgcn_global_load_lds(
      (const __attribute__((address_space(1))) void*)g,
      (__attribute__((address_space(3))) void*)l, 16, 0, 0);
}

// ---------------- kernel 0: pack aW1 into MFMA-fragment-sequential layout ----
__global__ __launch_bounds__(256) void k_prep(const float* __restrict__ aW1,
                                              unsigned short* __restrict__ hi,
                                              unsigned short* __restrict__ lo) {
  int tau = blockIdx.x * 256 + threadIdx.x;   // (ks,t,lane) tuple, 4096 total
  if (tau >= 4096) return;
  int ks = tau >> 8, t = (tau >> 6) & 3, lane = tau & 63;
  int n = t * 16 + (lane & 15);
  int kb = ks * 32 + (lane >> 4) * 8;
#pragma unroll
  for (int j = 0; j < 8; j++) {
    float v = aW1[(kb + j) * H_ATT + n];
    unsigned short h = bf16_rn(v);
    unsigned short l = bf16_rn(v - bf16_f(h));
    hi[tau * 8 + j] = h;
    lo[tau * 8 + j] = l;
  }
}

// ---------------- kernel 1: score MLP -> sigmoid weights (verified m97-style) --
#define BM 64
#define AUNIT 1040   // 1024 + 16B pad

__global__ __launch_bounds__(256) void k_scores(
    const float* __restrict__ x,
    const unsigned short* __restrict__ w1p_hi,
    const unsigned short* __restrict__ w1p_lo,
    const float* __restrict__ ab1, const float* __restrict__ aW2,
    const float* __restrict__ ab2, float* __restrict__ wout) {
  __shared__ __align__(16) char Asm[16 * AUNIT];
  __shared__ __align__(16) char Bh[8192];
  __shared__ __align__(16) char Bl[8192];

  int tid = threadIdx.x;
  int wave = tid >> 6, lane = tid & 63;
  int c0 = lane & 15, quad = lane >> 4;
  int rowBase0 = blockIdx.x * BM;

  f32x4 acc[4];
#pragma unroll
  for (int t = 0; t < 4; t++) acc[t] = (f32x4){0.f, 0.f, 0.f, 0.f};

  const int r = wave * 16 + c0;        // row within block this lane computes
  const int uA = r >> 2;
  const int aoff = uA * AUNIT + (r & 3) * 256 + quad * 32;

  for (int c = 0; c < 8; c++) {
    size_t kb = (size_t)c * 256;   // byte offset within a row
#pragma unroll
    for (int i = 0; i < 4; i++) {
      int u = wave * 4 + i;
      const char* g = (const char*)x +
          (size_t)(rowBase0 + u * 4 + (lane >> 4)) * 2048 + kb + (size_t)(lane & 15) * 16;
      load_lds16(g, Asm + u * AUNIT);
    }
#pragma unroll
    for (int i = 0; i < 4; i++) {
      int v = wave * 4 + i;    // 0..15: 0-7 hi, 8-15 lo
      int vv = v & 7;
      const char* gsrc = (v < 8) ? (const char*)w1p_hi : (const char*)w1p_lo;
      char* ldst = (v < 8) ? Bh : Bl;
      load_lds16(gsrc + (size_t)c * 8192 + vv * 1024 + (size_t)lane * 16,
                 ldst + vv * 1024);
    }
    __syncthreads();   // drains DMA (vmcnt) + makes LDS visible

#pragma unroll
    for (int stp = 0; stp < 2; stp++) {
      const float4 a0v = *reinterpret_cast<const float4*>(Asm + aoff + stp * 128);
      const float4 a1v = *reinterpret_cast<const float4*>(Asm + aoff + stp * 128 + 16);
      bf16x8 afh, afl;
      cvt_hilo(a0v, a1v, afh, afl);
      bf16x8 bfh[4], bfl[4];
#pragma unroll
      for (int t = 0; t < 4; t++) {
        bfh[t] = *reinterpret_cast<const bf16x8*>(Bh + (stp * 4 + t) * 1024 + lane * 16);
        bfl[t] = *reinterpret_cast<const bf16x8*>(Bl + (stp * 4 + t) * 1024 + lane * 16);
      }
#pragma unroll
      for (int t = 0; t < 4; t++) {
        acc[t] = __builtin_amdgcn_mfma_f32_16x16x32_bf16(afl, bfh[t], acc[t], 0, 0, 0);
        acc[t] = __builtin_amdgcn_mfma_f32_16x16x32_bf16(afh, bfl[t], acc[t], 0, 0, 0);
        acc[t] = __builtin_amdgcn_mfma_f32_16x16x32_bf16(afh, bfh[t], acc[t], 0, 0, 0);
      }
    }
    __syncthreads();   // protect LDS before next chunk overwrites
  }

  // epilogue: h = gelu(acc + ab1); score = h @ aW2 + ab2; w = sigmoid(score)
  float w2v[4], b1v[4];
#pragma unroll
  for (int t = 0; t < 4; t++) {
    w2v[t] = aW2[t * 16 + c0];
    b1v[t] = ab1[t * 16 + c0];
  }
  float bias2 = ab2[0];
  float p[4] = {0.f, 0.f, 0.f, 0.f};
#pragma unroll
  for (int t = 0; t < 4; t++)
#pragma unroll
    for (int rr = 0; rr < 4; rr++) {
      float h = gelu_f(acc[t][rr] + b1v[t]);
      p[rr] += h * w2v[t];
    }
#pragma unroll
  for (int off = 1; off < 16; off <<= 1)
#pragma unroll
    for (int rr = 0; rr < 4; rr++) p[rr] += __shfl_xor(p[rr], off, 64);
  if (c0 == 0) {
    int row = rowBase0 + wave * 16 + quad * 4;
#pragma unroll
    for (int rr = 0; rr < 4; rr++) {
      float sc = p[rr] + bias2;
      wout[row + rr] = 1.0f / (1.0f + expf(-sc));
    }
  }
}

// ---------------- kernel 1b: per-bag top-k threshold (once per bag) ----------
__global__ __launch_bounds__(256) void k_thresh(const float* __restrict__ wout,
                                                unsigned int* __restrict__ thr) {
  int b = blockIdx.x;
  int tid = threadIdx.x;
  const float* w = wout + b * N_INST;

  unsigned int v[32];
#pragma unroll
  for (int j = 0; j < 32; j++) v[j] = __float_as_uint(w[j * 256 + tid]);

  __shared__ int red[2][4];
  int lane = tid & 63, wv = tid >> 6;
  int pb = 0;
  auto blocksum = [&](int c) -> int {
#pragma unroll
    for (int off = 32; off > 0; off >>= 1) c += __shfl_down(c, off, 64);
    if (lane == 0) red[pb][wv] = c;
    __syncthreads();
    int s = red[pb][0] + red[pb][1] + red[pb][2] + red[pb][3];
    pb ^= 1;
    return s;
  };

  unsigned int lo = 0u, hi = 0x3F800001u;
  while (hi - lo > 1u) {
    unsigned int mid = lo + ((hi - lo) >> 1);
    int c = 0;
#pragma unroll
    for (int j = 0; j < 32; j++) c += (v[j] >= mid) ? 1 : 0;
    if (blocksum(c) >= TOPK_K) lo = mid; else hi = mid;
  }
  unsigned int T = lo;
  int c1 = 0;
#pragma unroll
  for (int j = 0; j < 32; j++) c1 += (v[j] > T) ? 1 : 0;
  c1 = blocksum(c1);
  int needed = TOPK_K - c1;  // >= 1
  unsigned int tm = 0;
#pragma unroll
  for (int j = 0; j < 32; j++) tm |= (v[j] == T ? 1u : 0u) << j;
  int lom = -1, him = N_INST - 1;
  while (him - lom > 1) {
    int mid = (lom + him) >> 1;
    unsigned int mask = 0u;
    if (mid >= tid) {
      unsigned int jmax = (unsigned int)(mid - tid) >> 8;
      mask = (2u << jmax) - 1u;
    }
    if (blocksum((int)__popc(tm & mask)) >= needed) him = mid; else lom = mid;
  }
  if (tid == 0) {
    thr[b * 2] = T;
    thr[b * 2 + 1] = (unsigned int)him;   // Icut
  }
}

// ---------------- kernel 2: selection + weighted gather ----------------
__global__ __launch_bounds__(256) void k_gather(const float* __restrict__ x,
                                                const float* __restrict__ wout,
                                                const unsigned int* __restrict__ thr,
                                                float* __restrict__ part3) {
  int b = blockIdx.x >> 6;
  int blk = blockIdx.x & 63;
  int tid = threadIdx.x;
  const float* w = wout + b * N_INST;

  unsigned int T = thr[b * 2];
  int Icut = (int)thr[b * 2 + 1];

  __shared__ int idxs[128];
  __shared__ float wgts[128];
  __shared__ int wcnt[2];
  __shared__ float4 xfer[128];

  int lane = tid & 63;
  int r = blk * 128 + tid;
  bool sel = false;
  float wvv = 0.f;
  int pos = 0;
  if (tid < 128) {
    wvv = w[r];
    unsigned int wu = __float_as_uint(wvv);
    sel = (wu > T) || (wu == T && r <= Icut);
    unsigned long long m = __ballot(sel);
    pos = __popcll(m & ((1ull << lane) - 1ull));
    if (lane == 0) wcnt[tid >> 6] = __popcll(m);
  }
  __syncthreads();
  int total = wcnt[0] + wcnt[1];
  if (sel) {
    int base = (tid >= 64) ? wcnt[0] : 0;
    idxs[base + pos] = r;
    wgts[base + pos] = wvv;
  }
  __syncthreads();

  int half = tid >> 7;
  int L = tid & 127;
  float4 acc = {0.f, 0.f, 0.f, 0.f};
  const float* xb = x + (size_t)b * N_INST * D_DIM;
  int i2 = total & ~1;
#pragma unroll 4
  for (int i = 0; i < i2; i += 2) {
    int rr = idxs[i + half];
    float ww = wgts[i + half];
    const float4 xv = *reinterpret_cast<const float4*>(xb + (size_t)rr * D_DIM + L * 4);
    acc.x += ww * xv.x; acc.y += ww * xv.y; acc.z += ww * xv.z; acc.w += ww * xv.w;
  }
  if ((total & 1) && half == 0) {
    int rr = idxs[i2];
    float ww = wgts[i2];
    const float4 xv = *reinterpret_cast<const float4*>(xb + (size_t)rr * D_DIM + L * 4);
    acc.x += ww * xv.x; acc.y += ww * xv.y; acc.z += ww * xv.z; acc.w += ww * xv.w;
  }
  if (half == 1) xfer[L] = acc;
  __syncthreads();
  if (half == 0) {
    float4 o = xfer[L];
    acc.x += o.x; acc.y += o.y; acc.z += o.z; acc.w += o.w;
    *reinterpret_cast<float4*>(part3 + (size_t)(b * 64 + blk) * D_DIM + L * 4) = acc;
  }
}

// ---------------- projection MLP: split-K x16; layer2 accumulates into out ----
__global__ __launch_bounds__(256) void k_proj1(const float* __restrict__ part3,
                                               const float* __restrict__ pW1,
                                               float* __restrict__ part1,
                                               const float* __restrict__ pb2,
                                               float* __restrict__ out) {
  int jt = blockIdx.x & 7, kt = blockIdx.x >> 3;   // kt in [0,16)
  __shared__ float emb_s[256];                      // [8 bags][32 dims]
  int tid = threadIdx.x;
  int col = tid & 63, bg = tid >> 6;
  if (kt == 0) {
    float bz = pb2[jt * 64 + col];
    out[(bg * 2) * 512 + jt * 64 + col] = bz;
    out[(bg * 2 + 1) * 512 + jt * 64 + col] = bz;
  }
  {
    int b = tid >> 5, d0 = tid & 31;
    const float* p = part3 + (size_t)b * 64 * 512 + kt * 32 + d0;
    float e = 0.f;
#pragma unroll 8
    for (int j = 0; j < 64; j++) e += p[j * 512];
    emb_s[b * 32 + d0] = e * (1.0f / TOPK_K);
  }
  __syncthreads();
  float a0 = 0.f, a1 = 0.f;
  const float* wrow = pW1 + (size_t)(kt * 32) * 512 + jt * 64 + col;
#pragma unroll 8
  for (int q = 0; q < 32; q++) {
    float wq = wrow[q * 512];
    a0 += emb_s[(bg * 2) * 32 + q] * wq;
    a1 += emb_s[(bg * 2 + 1) * 32 + q] * wq;
  }
  part1[kt * 4096 + (bg * 2) * 512 + jt * 64 + col] = a0;
  part1[kt * 4096 + (bg * 2 + 1) * 512 + jt * 64 + col] = a1;
}

__global__ __launch_bounds__(256) void k_proj2(const float* __restrict__ part1,
                                               const float* __restrict__ pb1,
                                               const float* __restrict__ pW2,
                                               float* __restrict__ out) {
  int jt = blockIdx.x & 7, kt = blockIdx.x >> 3;   // kt in [0,16)
  __shared__ float h_s[256];                        // [8 bags][32 hidden]
  int tid = threadIdx.x;
  {
    int b = tid >> 5, j0 = tid & 31;
    int jj = kt * 32 + j0;
    float s = pb1[jj];
#pragma unroll
    for (int p = 0; p < 16; p++) s += part1[p * 4096 + b * 512 + jj];
    h_s[b * 32 + j0] = gelu_f(s);
  }
  __syncthreads();
  int col = tid & 63, bg = tid >> 6;
  float a0 = 0.f, a1 = 0.f;
  const float* wrow = pW2 + (size_t)(kt * 32) * 512 + jt * 64 + col;
#pragma unroll 8
  for (int q = 0; q < 32; q++) {
    float wq = wrow[q * 512];
    a0 += h_s[(bg * 2) * 32 + q] * wq;
    a1 += h_s[(bg * 2 + 1) * 32 + q] * wq;
  }
  atomicAdd(&out[(bg * 2) * 512 + jt * 64 + col], a0);
  atomicAdd(&out[(bg * 2 + 1) * 512 + jt * 64 + col], a1);
}

extern "C" void kernel_launch(void* const* d_in, const int* in_sizes, int n_in,
                              void* d_out, int out_size, void* d_ws, size_t ws_size,
                              hipStream_t stream) {
  (void)in_sizes; (void)n_in; (void)out_size; (void)ws_size;
  const float* x   = (const float*)d_in[0];
  const float* aW1 = (const float*)d_in[1];
  const float* ab1 = (const float*)d_in[2];
  const float* aW2 = (const float*)d_in[3];
  const float* ab2 = (const float*)d_in[4];
  const float* pW1 = (const float*)d_in[5];
  const float* pb1 = (const float*)d_in[6];
  const float* pW2 = (const float*)d_in[7];
  const float* pb2 = (const float*)d_in[8];

  float* out  = (float*)d_out;
  float* wout = out + B_BAGS * D_DIM;  // weights output region [8][8192]

  char* ws = (char*)d_ws;
  unsigned short* w1p_hi = (unsigned short*)(ws + WS_W1P_HI);
  unsigned short* w1p_lo = (unsigned short*)(ws + WS_W1P_LO);
  float* part3 = (float*)(ws + WS_PART3);
  float* part1 = (float*)(ws + WS_PART1);
  unsigned int* thr = (unsigned int*)(ws + WS_THRESH);

  k_prep<<<dim3(16), dim3(256), 0, stream>>>(aW1, w1p_hi, w1p_lo);
  k_scores<<<dim3(ROWS_TOTAL / BM), dim3(256), 0, stream>>>(x, w1p_hi, w1p_lo, ab1, aW2, ab2, wout);
  k_thresh<<<dim3(B_BAGS), dim3(256), 0, stream>>>(wout, thr);
  k_gather<<<dim3(B_BAGS * 64), dim3(256), 0, stream>>>(x, wout, thr, part3);
  k_proj1<<<dim3(128), dim3(256), 0, stream>>>(part3, pW1, part1, pb2, out);
  k_proj2<<<dim3(128), dim3(256), 0, stream>>>(part1, pb1, pW2, out);
}